// Round 4
// baseline (157.565 us; speedup 1.0000x reference)
//
#include <hip/hip_runtime.h>
#include <math.h>

#define MARGIN 0.4f
#define EPSF   1e-3f
#define SCALE  64.0f
#define EPT    16     // float4s per thread
#define BLK    256    // threads per block

typedef float vfloat4 __attribute__((ext_vector_type(4)));

// Single fused kernel, block-contiguous mapping.
// Each block owns float4 indices [b*BLK*EPT, (b+1)*BLK*EPT) — a contiguous
// 256 KB span covering at most 2 rows (C = 100000 floats/row, C % 4 == 0 so
// no float4 straddles a row boundary). Blocks that own a target element
// (label position of a positive row) redundantly compute the mean/std of the
// clipped norms and patch the one element in-stream.
__global__ __launch_bounds__(BLK)
void adaface_fused_kernel(const float* __restrict__ in_s,
                          const float* __restrict__ norms,
                          const int* __restrict__ labels,
                          float* __restrict__ out_s,
                          long n4, long n, int B, int C) {
    const vfloat4* __restrict__ in  = (const vfloat4*)in_s;
    vfloat4* __restrict__ out = (vfloat4*)out_s;

    int  tid    = threadIdx.x;
    long f4base = (long)blockIdx.x * (BLK * EPT);
    long fstart = f4base * 4;
    long fend   = fstart + (long)BLK * EPT * 4;

    // rows this block can touch (span 256KB < one 400KB row => at most 2 rows)
    int  row0     = (int)(fstart / C);
    long rowsplit = (long)(row0 + 1) * C;     // first flat index of row0+1
    int  r1       = row0 + 1;

    int  lab0 = (row0 < B) ? labels[row0] : -1;
    int  lab1 = (r1   < B) ? labels[r1]   : -1;
    long t0 = (lab0 != -1) ? (long)row0 * C + lab0 : (long)-1;
    long t1 = (lab1 != -1) ? (long)r1   * C + lab1 : (long)-1;
    bool has0 = (t0 >= fstart) && (t0 < fend);
    bool has1 = (t1 >= fstart) && (t1 < fend);
    bool full = (f4base + (long)BLK * EPT) <= n4;

    if (full && !(has0 || has1)) {
        // clean streaming path (~85% of blocks)
#pragma unroll
        for (int j = 0; j < EPT; ++j) {
            long k = f4base + j * BLK + tid;
            vfloat4 v = __builtin_nontemporal_load(&in[k]);
            v *= SCALE;
            __builtin_nontemporal_store(v, &out[k]);
        }
    } else {
        float v0 = 0.0f, v1 = 0.0f;
        if (has0 || has1) {
            // block-redundant stats over all B rows (8 KB, L2-resident)
            __shared__ float ra[4], rb[4];
            __shared__ float sm[3];   // mean, std, cnt

            float lsn[4]; bool lp[4];
            float lsum = 0.0f, lcnt = 0.0f;
#pragma unroll
            for (int q = 0; q < 4; ++q) {
                int r = tid + q * BLK;
                bool p = false; float s = 0.0f;
                if (r < B) {
                    int lb = labels[r];
                    p = (lb != -1);
                    s = fminf(fmaxf(norms[r], 1e-3f), 100.0f);
                }
                lp[q] = p; lsn[q] = s;
                if (p) { lsum += s; lcnt += 1.0f; }
            }
            int lane = tid & 63, wv = tid >> 6;
            for (int off = 32; off >= 1; off >>= 1) {
                lsum += __shfl_down(lsum, off);
                lcnt += __shfl_down(lcnt, off);
            }
            if (lane == 0) { ra[wv] = lsum; rb[wv] = lcnt; }
            __syncthreads();
            if (tid == 0) {
                float s = ra[0] + ra[1] + ra[2] + ra[3];
                float c = rb[0] + rb[1] + rb[2] + rb[3];
                sm[0] = s / c; sm[2] = c;
            }
            __syncthreads();
            float mean = sm[0];
            float lvar = 0.0f;
#pragma unroll
            for (int q = 0; q < 4; ++q) {
                if (lp[q]) { float d = lsn[q] - mean; lvar += d * d; }
            }
            for (int off = 32; off >= 1; off >>= 1) lvar += __shfl_down(lvar, off);
            if (lane == 0) ra[wv] = lvar;
            __syncthreads();
            if (tid == 0) {
                float v = ra[0] + ra[1] + ra[2] + ra[3];
                sm[1] = sqrtf(v / (sm[2] - 1.0f));
            }
            __syncthreads();
            float stdv = sm[1];

            if (has0) {
                float sn0 = fminf(fmaxf(norms[row0], 1e-3f), 100.0f);
                float ms  = (sn0 - mean) / (stdv + EPSF);
                float x   = in_s[t0];
                float th  = acosf(x) - MARGIN * ms;
                th = fminf(fmaxf(th, EPSF), (float)M_PI - EPSF);
                v0 = (cosf(th) - (MARGIN + MARGIN * ms)) * SCALE;
            }
            if (has1) {
                float sn1 = fminf(fmaxf(norms[r1], 1e-3f), 100.0f);
                float ms  = (sn1 - mean) / (stdv + EPSF);
                float x   = in_s[t1];
                float th  = acosf(x) - MARGIN * ms;
                th = fminf(fmaxf(th, EPSF), (float)M_PI - EPSF);
                v1 = (cosf(th) - (MARGIN + MARGIN * ms)) * SCALE;
            }
        }
        // guarded streaming with branchless substitution
#pragma unroll
        for (int j = 0; j < EPT; ++j) {
            long k = f4base + j * BLK + tid;
            if (k < n4) {
                long f = k * 4;
                vfloat4 v = __builtin_nontemporal_load(&in[k]);
                v *= SCALE;
                bool  in0 = f < rowsplit;
                long  tg  = in0 ? t0 : t1;
                float tv  = in0 ? v0 : v1;
                long  dl  = tg - f;
                v.x = (dl == 0) ? tv : v.x;
                v.y = (dl == 1) ? tv : v.y;
                v.z = (dl == 2) ? tv : v.z;
                v.w = (dl == 3) ? tv : v.w;
                __builtin_nontemporal_store(v, &out[k]);
            }
        }
    }

    // scalar tail (n % 4 != 0 leftovers; empty here since n % 4 == 0)
    long gid = (long)blockIdx.x * BLK + tid;
    long nth = (long)gridDim.x * BLK;
    for (long k = n4 * 4 + gid; k < n; k += nth) {
        out_s[k] = in_s[k] * SCALE;
    }
}

extern "C" void kernel_launch(void* const* d_in, const int* in_sizes, int n_in,
                              void* d_out, int out_size, void* d_ws, size_t ws_size,
                              hipStream_t stream) {
    const float* logits = (const float*)d_in[0];
    const float* norms  = (const float*)d_in[1];
    const int*   labels = (const int*)d_in[2];
    float* out = (float*)d_out;

    int  B = in_sizes[2];          // 1024
    long n = (long)in_sizes[0];    // 102,400,000
    int  C = (int)(n / B);         // 100,000

    long n4 = n / 4;
    long grid_l = (n4 + (long)BLK * EPT - 1) / ((long)BLK * EPT);  // 6250
    int  grid = (int)grid_l;

    adaface_fused_kernel<<<grid, BLK, 0, stream>>>(
        logits, norms, labels, out, n4, n, B, C);
}